// Round 8
// baseline (197.251 us; speedup 1.0000x reference)
//
#include <hip/hip_runtime.h>

// NodeEdgeProjection: out[b, e, f] = x[b, e/127, f]
// B=128, N=128, n_edges = 128*127 = 16256, F=64, fp32. 533 MB written.
//
// Round-7: R6 diagnostic showed a pure 533 MB fill in the grid-stride
// 256x256 config costs 88 us (6.06 TB/s) -- 15 us faster than our best
// gather. Hypothesis: the winning property is INSTANTANEOUS WHOLE-GRID
// CONTIGUITY (each grid-stride iteration writes one contiguous ~1 MB window
// that marches), which none of the multi-stream variants had (R5's 1024
// independent spans: 119.7; R3's 16384 tiny spans: 103.1).
//
// This kernel = ws_fill533's exact store structure (256 blocks x 256 thr,
// plain stores, 508 iterations, no tail) + the gather value supplied by a
// 2-deep prefetch pipeline: load for iter k+2 (L1/L2-resident x, 4x lane
// broadcast of one 256 B line per wave), store iter k. One window of stores
// (~400 cy) hides the ~200 cy L2 load.

typedef float f32x4 __attribute__((ext_vector_type(4)));

constexpr unsigned Bn = 128;
constexpr unsigned Nn = 128;
constexpr unsigned NE = Nn * (Nn - 1);      // 16256
constexpr unsigned F4 = 16;                 // float4 per 64-float row
constexpr unsigned TOTAL4 = Bn * NE * F4;   // 33,292,288
constexpr unsigned NTH = 256 * 256;         // 65536 threads
constexpr unsigned ITERS = TOTAL4 / NTH;    // 508, exact (no tail)

__device__ __forceinline__ unsigned src_index(unsigned o) {
    unsigned f4   = o & (F4 - 1);
    unsigned rest = o >> 4;          // b*NE + e
    unsigned e    = rest % NE;       // magic-mul
    unsigned b    = rest / NE;
    unsigned node = e / (Nn - 1);    // magic-mul
    return (b * Nn + node) * F4 + f4;
}

__global__ __launch_bounds__(256) void node_edge_gs_pipe(
    const f32x4* __restrict__ x, f32x4* __restrict__ out) {
    const unsigned t = blockIdx.x * 256 + threadIdx.x;

    // 2-deep prefetch pipeline.
    f32x4 v0 = x[src_index(t)];
    f32x4 v1 = x[src_index(t + NTH)];

    unsigned o = t;
    #pragma unroll 2
    for (unsigned k = 0; k < ITERS - 2; ++k) {
        f32x4 vn = x[src_index(o + 2 * NTH)];
        out[o] = v0;
        v0 = v1;
        v1 = vn;
        o += NTH;
    }
    out[o] = v0;
    o += NTH;
    out[o] = v1;
}

extern "C" void kernel_launch(void* const* d_in, const int* in_sizes, int n_in,
                              void* d_out, int out_size, void* d_ws, size_t ws_size,
                              hipStream_t stream) {
    const f32x4* x = (const f32x4*)d_in[0];
    f32x4* out = (f32x4*)d_out;

    node_edge_gs_pipe<<<256, 256, 0, stream>>>(x, out);
}

// Round 9
// 106.013 us; speedup vs baseline: 1.8606x; 1.8606x over previous
//
#include <hip/hip_runtime.h>

// NodeEdgeProjection: out[b, e, f] = x[b, e/127, f]
// B=128, N=128, n_edges = 128*127, F=64, fp32. 533 MB written, 4 MB read.
//
// Round-8 synthesis. Measured ladder:
//   fill533 (no loads, 1 marching window)            88.0 us  <- floor ref
//   R3 tiny blocks (preloaded value, 2048+ spans)   103.1 us
//   R5 per-wave streams (preloaded, 1024 streams)   119.7 us
//   R8 grid-stride (in-loop dependent loads)        197.3 us
// => need BOTH store-only inner loop AND few tight sequential windows.
//
// This kernel: fill533's dispatch shape (256 blocks x 256 thr, 1 block/CU,
// plain stores). Block owns 64 CONSECUTIVE pairs = one 2 MB sequential
// stream. Per pair: one 256 B row load, prefetched 1 pair ahead (slack =
// 32 KB of stores ~ 3000 cy >> 900 cy HBM latency), then 8 block-wide
// contiguous 4 KB stores. Loads amortize to 1 per 32 KB stored.

typedef float f32x4 __attribute__((ext_vector_type(4)));

constexpr unsigned Nn   = 128;
constexpr unsigned REP  = Nn - 1;            // 127 replica rows per pair
constexpr unsigned F4   = 16;                // f32x4 per 64-float row
constexpr unsigned PAIRS = 128 * 128;        // 16384 (b,node) pairs
constexpr unsigned PPB  = PAIRS / 256;       // 64 pairs per block

__global__ __launch_bounds__(256) void node_edge_seq(
    const f32x4* __restrict__ x, f32x4* __restrict__ out) {
    const unsigned tid  = threadIdx.x;
    const unsigned f4   = tid & (F4 - 1);     // quad 0..15
    const unsigned row  = tid >> 4;           // row-in-chunk 0..15

    const unsigned pair0 = blockIdx.x * PPB;  // 64 consecutive pairs

    // Prefetch pair 0's row.
    f32x4 v = x[pair0 * F4 + f4];

    f32x4* dst = out + (size_t)pair0 * REP * F4;

    for (unsigned p = 0; p < PPB; ++p) {
        // Prefetch next pair's row; its wait lands after this pair's stores
        // are issued (compiler schedules; 8 store instrs of slack).
        f32x4 vnext;
        if (p + 1 < PPB) vnext = x[(pair0 + p + 1) * F4 + f4];

        // 127 rows = 7 full 16-row chunks + 15-row tail; each chunk is a
        // block-wide contiguous 4 KB store (256 thr x 16 B).
        f32x4* dp = dst + (size_t)p * REP * F4 + row * F4 + f4;
        #pragma unroll
        for (unsigned j = 0; j < 8; ++j) {
            unsigned r = j * 16 + row;
            if (r < REP) dp[j * 16 * F4] = v;
        }

        v = vnext;
    }
}

extern "C" void kernel_launch(void* const* d_in, const int* in_sizes, int n_in,
                              void* d_out, int out_size, void* d_ws, size_t ws_size,
                              hipStream_t stream) {
    const f32x4* x = (const f32x4*)d_in[0];
    f32x4* out = (f32x4*)d_out;

    node_edge_seq<<<256, 256, 0, stream>>>(x, out);
}

// Round 10
// 99.787 us; speedup vs baseline: 1.9767x; 1.0624x over previous
//
#include <hip/hip_runtime.h>

// NodeEdgeProjection: out[b, e, f] = x[b, e/127, f]
// B=128, N=128, n_edges=128*127, F=64, fp32. 533 MB written, 4 MB read.
//
// Round-9: window-tightness theory. Ladder (wall us):
//   fill533 one marching 1MB window           88.0   <- same-size floor
//   R3 tiny+nt (~2048 resident -> 64MB win)  103.1   <- best gather
//   R9 256 streams (533MB window always)     106.0
//   others (fat/nt/stride/per-wave)          106-120
// Composite R6 arithmetic: fill's DEVICE time is 88; R3's device time is
// 103.1 minus fixed replay overhead h -- real gap may be only ~5 us.
//
// This round: R3 VERBATIM + 96 KB dummy LDS to cap residency at 1 block/CU.
// Active blocks then span ~256 consecutive IDs -> rolling write window
// shrinks 64 MB -> 8 MB (fill-like). Per-CU shape unchanged (4 waves, 32 KB
// store bursts, value preloaded, store-only inner loop, nt stores).

typedef float f32x4 __attribute__((ext_vector_type(4)));

constexpr unsigned Bn = 128;
constexpr unsigned Nn = 128;
constexpr unsigned NE = Nn * (Nn - 1);   // 16256
constexpr unsigned F4 = 16;              // f32x4 per 64-float row

__global__ __launch_bounds__(256) void node_edge_bcast_1cu(
    const f32x4* __restrict__ x, f32x4* __restrict__ out) {
    // 96 KB LDS -> at most 1 resident block per CU (160 KB pool).
    __shared__ f32x4 occupancy_pad[6144];

    const unsigned blk  = blockIdx.x;        // = b*Nn + node
    const unsigned tid  = threadIdx.x;
    const unsigned f4   = tid & (F4 - 1);    // feature quad 0..15
    const unsigned row0 = tid >> 4;          // starting replica row 0..15

    const f32x4 v = x[blk * F4 + f4];

    const unsigned b    = blk >> 7;          // / Nn
    const unsigned node = blk & (Nn - 1);    // % Nn
    f32x4* dst = out + (b * NE + node * (Nn - 1)) * F4;

    #pragma unroll
    for (unsigned r = row0; r < Nn - 1; r += 16) {
        __builtin_nontemporal_store(v, &dst[r * F4 + f4]);
    }

    // Keep the LDS allocation live; blockIdx range is opaque to the
    // compiler so this guard is never provably dead, and never executes.
    if (blk == 0xFFFFFFFFu) {
        occupancy_pad[tid] = v;
        __syncthreads();
        dst[0] = occupancy_pad[255 - tid];
    }
}

extern "C" void kernel_launch(void* const* d_in, const int* in_sizes, int n_in,
                              void* d_out, int out_size, void* d_ws, size_t ws_size,
                              hipStream_t stream) {
    const f32x4* x = (const f32x4*)d_in[0];
    f32x4* out = (f32x4*)d_out;

    node_edge_bcast_1cu<<<Bn * Nn, 256, 0, stream>>>(x, out);
}